// Round 5
// baseline (5274.512 us; speedup 1.0000x reference)
//
#include <hip/hip_runtime.h>
#include <stdint.h>

typedef _Float16 f16;
typedef _Float16 half8 __attribute__((ext_vector_type(8)));
typedef _Float16 half4 __attribute__((ext_vector_type(4)));
typedef float float4v __attribute__((ext_vector_type(4)));
typedef float float2v __attribute__((ext_vector_type(2)));
typedef unsigned int u32;

#define MFMA16(A, B, C) __builtin_amdgcn_mfma_f32_16x16x32_f16((A), (B), (C), 0, 0, 0)

static constexpr int Bsz = 512, Tsz = 512, Fsz = 128, Lsz = 512;
static constexpr int NPACK = 2176;  // [r|z|in|hn] (4*512) + y (128)
static constexpr float LO_S = 2048.0f, LO_R = 1.0f / 2048.0f;

// ws layout (bytes)
static constexpr size_t WSZ_FRAG  = (size_t)(NPACK / 16) * 16 * 64 * 8 * 2;  // 2,228,224
static constexpr size_t OFF_WHI   = 0;
static constexpr size_t OFF_WLO   = OFF_WHI + WSZ_FRAG;
static constexpr size_t OFF_BIAS  = OFF_WLO + WSZ_FRAG;                  // 4,456,448
static constexpr size_t OFF_HX    = OFF_BIAS + 16384;   // 2 bufs x 16g x 16m x 4KB
static constexpr size_t OFF_FLAGS = OFF_HX + (size_t)2 * 1024 * 1024;    // 8192 ints

// h exchange block (per buf,g,mm), 4KB, WRITE-DENSE layout:
//   hi region [0,2048):  mt*1024 + n*64 + chunk*16 + half*8   (row = mt*16+n of the
//   lo region [2048,4096): same offsets                         group; k-in-slice =
//   chunk*8 + half*4 + elem)
// Producer store instructions are wave-dense (512B); consumer 16B fragment reads
// (mt*1024 + n*64 + q*16) are bank-balanced in LDS (8 slots x 8 lanes per 128B).

// LDS layout (bytes); dynamic
static constexpr int LDS_H  = 0;        // 4 waves x 16KB staged member slices
static constexpr int EXS = 37;          // odd stride: no even-bank aliasing
static constexpr int LDS_EX = 65536;    // f32 [4t][4w][32col][EXS]
static constexpr int LDS_YP = LDS_EX + 16 * 32 * EXS * 4;  // f32 [4w][16row][17]
static constexpr int LDS_TOT = LDS_YP + 4 * 16 * 17 * 4;   // 145,664

// async global->LDS, 16B/lane, sc1 (device scope: bypass L1/L2, read at L3)
__device__ __forceinline__ void async16(const void* g, void* l) {
  __builtin_amdgcn_global_load_lds((const __attribute__((address_space(1))) u32*)g,
                                   (__attribute__((address_space(3))) u32*)l, 16, 0, 16);
}

__device__ __forceinline__ float sigm(float x) { return 1.0f / (1.0f + __expf(-x)); }
__device__ __forceinline__ float tanh_(float x) { return 1.0f - 2.0f / (__expf(2.0f * x) + 1.0f); }

// ---------------- prep kernel 1: fold + split + fragment-pack weights ----------------
// packed col c: [0,1024): r/z combined = M[l][c] + Whh[c][l]
//               [1024,1536): i_n       = M[l][c]
//               [1536,2048): h_n       = Whh[c-512][l]
//               [2048,2176): y         = Wd[c-2048][l]
// where M[l][j] = sum_f Wd[f][l] * Wih[j][f]  (dense layer folded into input weights)
__global__ void k_pack(const float* __restrict__ Wih, const float* __restrict__ Whh,
                       const float* __restrict__ Wd, f16* __restrict__ whiF,
                       f16* __restrict__ wloF) {
  const int c = blockIdx.y;                      // 0..2175 (uniform per block)
  const int l = blockIdx.x * 256 + threadIdx.x;  // 0..511 (contraction index)
  float v;
  if (c < 1536) {
    const float* wih = Wih + c * 128;
    float acc = 0.f;
#pragma unroll 8
    for (int f = 0; f < 128; ++f) acc = fmaf(Wd[f * 512 + l], wih[f], acc);
    v = acc;
    if (c < 1024) v += Whh[c * 512 + l];
  } else if (c < 2048) {
    v = Whh[(c - 512) * 512 + l];
  } else {
    v = Wd[(c - 2048) * 512 + l];
  }
  f16 hi = (f16)v;
  f16 lo = (f16)((v - (float)hi) * LO_S);  // scaled: raw residual is fp16-subnormal
  // B-fragment layout for mfma 16x16x32: lane=q*16+n holds B[k=32*ks+8*q+j][n]
  const int chunk = c >> 4, ks = l >> 5, q = (l >> 3) & 3, j = l & 7, n = c & 15;
  const size_t idx = (((size_t)(chunk * 16 + ks)) * 64 + q * 16 + n) * 8 + j;
  whiF[idx] = hi;
  wloF[idx] = lo;
}

// ---------------- prep kernel 2: h records (buffer 0), biases, flags ----------------
__global__ void k_init(const float* __restrict__ h0, const float* __restrict__ Wih,
                       const float* __restrict__ bih, const float* __restrict__ bhh,
                       const float* __restrict__ bd, f16* __restrict__ hx,
                       float* __restrict__ biasP, int* __restrict__ flags) {
  const int t = blockIdx.x * 256 + threadIdx.x;
  if (t < Bsz * Lsz) {
    const int row = t >> 9, col = t & 511;
    float v = h0[t];
    f16 hi = (f16)v;
    f16 lo = (f16)((v - (float)hi) * LO_S);
    const int g = row >> 5, rl = row & 31, mm = col >> 5, cs = col & 31;
    const size_t b = (size_t)g * 65536 + (size_t)mm * 4096 + (rl >> 4) * 1024 +
                     (rl & 15) * 64 + (cs >> 3) * 16 + ((cs >> 2) & 1) * 8 + (cs & 3) * 2;
    *(f16*)((char*)hx + b) = hi;          // buffer 0 (kernel-end release -> L3)
    *(f16*)((char*)hx + b + 2048) = lo;
  }
  if (t < NPACK) {
    float v;
    if (t < 1536) {
      float a = bih[t];  // + (Wih @ bd) fold of the dense bias
      for (int f = 0; f < 128; ++f) a = fmaf(Wih[t * 128 + f], bd[f], a);
      if (t < 1024) a += bhh[t];
      v = a;
    } else if (t < 2048) {
      v = bhh[t - 512];
    } else {
      v = bd[t - 2048];
    }
    biasP[t] = v;
  }
  if (t < 8192) flags[t] = 0;
}

// ---------------- main persistent kernel ----------------
// 16 groups x 32 rows; 16 members x 32 gate-cols; wave v = K-quarter [128v,128v+128)
// Exchange schedule (sc1/L3 transport, proven):
//   batch-poll (4 flags, nothing in flight) -> batch-issue 16 global_load_lds ->
//   counted vmcnt(12/8/4/0) per K-slice so GEMM overlaps staging. Per-member
//   single-writer flags; wave waits only on its own 4 source members.
// y = dense(h) balanced over all 16 members (tile m>>1, row-half m&1), inline.
__global__ __launch_bounds__(256, 1) void k_main(
    const float* __restrict__ h0, const f16* __restrict__ whiF,
    const f16* __restrict__ wloF, const float* __restrict__ biasP,
    f16* __restrict__ hx, int* __restrict__ flags, float* __restrict__ out) {
  extern __shared__ char dsm[];
  float* ex = (float*)(dsm + LDS_EX);
  float* yp = (float*)(dsm + LDS_YP);

  const int bid = blockIdx.x;
  const int g = bid & 15;   // group: rows [32g, 32g+32)
  const int m = bid >> 4;   // member: gate-cols [32m, 32m+32) of each type
  const int tid = threadIdx.x;
  const int v = tid >> 6, lane = tid & 63, q = lane >> 4, n = lane & 15;
  const int yt = m >> 1, mty = m & 1;  // y tile / row-half of this member

  // ---- weight fragments resident in registers (hi+lo, this member's cols, this wave's K) ----
  const half8* whiV = (const half8*)whiF;
  const half8* wloV = (const half8*)wloF;
  half8 w_hi[4][2][4], w_lo[4][2][4];  // [type][ntile][ks]
#pragma unroll
  for (int t = 0; t < 4; ++t)
#pragma unroll
    for (int nt = 0; nt < 2; ++nt)
#pragma unroll
      for (int ks = 0; ks < 4; ++ks) {
        const int idx = ((t * 32 + m * 2 + nt) * 16 + v * 4 + ks) * 64 + lane;
        w_hi[t][nt][ks] = whiV[idx];
        w_lo[t][nt][ks] = wloV[idx];
      }
  half8 w_y[4];
#pragma unroll
  for (int ks = 0; ks < 4; ++ks)
    w_y[ks] = whiV[((128 + yt) * 16 + v * 4 + ks) * 64 + lane];

  // ---- per-thread gate-phase roles: row rl, 4 consecutive cols at c0 ----
  const int rl = tid >> 3, c0 = (tid & 7) * 4;
  float bias[4][4];
#pragma unroll
  for (int t = 0; t < 4; ++t)
#pragma unroll
    for (int cc = 0; cc < 4; ++cc) bias[t][cc] = biasP[t * 512 + m * 32 + c0 + cc];
  float hreg[4];  // fp32 h for the z*h path (exact)
#pragma unroll
  for (int cc = 0; cc < 4; ++cc)
    hreg[cc] = h0[(size_t)(32 * g + rl) * 512 + m * 32 + c0 + cc];

  // y-reduce roles: 256 threads -> 16 rows x 16 cols of this member's y tile
  const int r16 = tid >> 4, c16 = tid & 15;
  const float by0 = biasP[2048 + yt * 16 + c16];
  const size_t outRowB = (size_t)(32 * g + mty * 16 + r16) * (Tsz * Fsz) + yt * 16 + c16;

  // producer-side store offset (hi region); lo at +2048
  const size_t recHi = (size_t)g * 65536 + (size_t)m * 4096 + (rl >> 4) * 1024 +
                       (rl & 15) * 64 + (c0 >> 3) * 16 + ((c0 >> 2) & 1) * 8;
  // consumer fragment base (hi), + ks*4096 per slice, +2048 for lo
  const int fragB0 = LDS_H + v * 16384 + 1024 * 0 + n * 64 + q * 16;

  int* fb = flags + g * 16;  // flag[g][mm] at fb[mm]
  const size_t grpB = (size_t)g * 65536;

  for (int s = 1; s <= 513; ++s) {
    // ---- drain (prev out stores) so vmcnt counting below is pure ----
    asm volatile("s_waitcnt vmcnt(0)" ::: "memory");

    // ---- batch-poll this wave's 4 source members (nothing in flight) ----
    if (s > 1) {
      int mn;
      do {
        const int f0 = __hip_atomic_load(fb + 4 * v + 0, __ATOMIC_RELAXED, __HIP_MEMORY_SCOPE_AGENT);
        const int f1 = __hip_atomic_load(fb + 4 * v + 1, __ATOMIC_RELAXED, __HIP_MEMORY_SCOPE_AGENT);
        const int f2 = __hip_atomic_load(fb + 4 * v + 2, __ATOMIC_RELAXED, __HIP_MEMORY_SCOPE_AGENT);
        const int f3 = __hip_atomic_load(fb + 4 * v + 3, __ATOMIC_RELAXED, __HIP_MEMORY_SCOPE_AGENT);
        mn = min(min(f0, f1), min(f2, f3));
        if (mn < s - 1) __builtin_amdgcn_s_sleep(1);
      } while (mn < s - 1);
    }
    __builtin_amdgcn_sched_barrier(0);

    // ---- batch-issue all 16 staging loads (4 per slice, slices in ks order) ----
    {
      const char* sb = (const char*)hx + (size_t)((s - 1) & 1) * 1048576 + grpB +
                       (size_t)(4 * v) * 4096 + lane * 16;
      char* db = dsm + LDS_H + v * 16384 + lane * 16;
#pragma unroll
      for (int j = 0; j < 4; ++j)
#pragma unroll
        for (int i = 0; i < 4; ++i)
          async16(sb + j * 4096 + i * 1024, db + j * 4096 + i * 1024);
    }

    // ---- GEMM: mt passes; per-slice counted waits overlap staging with MFMAs ----
    float4v yac = (float4v){0, 0, 0, 0};
#pragma unroll
    for (int mt = 0; mt < 2; ++mt) {
      float4v a_hh[4][2], a_ll[4][2];  // [type][nt]
#pragma unroll
      for (int t = 0; t < 4; ++t)
#pragma unroll
        for (int nt = 0; nt < 2; ++nt) {
          a_hh[t][nt] = (float4v){0, 0, 0, 0};
          a_ll[t][nt] = (float4v){0, 0, 0, 0};
        }
#pragma unroll
      for (int ks = 0; ks < 4; ++ks) {
        if (mt == 0) {
          if (ks == 0)      asm volatile("s_waitcnt vmcnt(12)" ::: "memory");
          else if (ks == 1) asm volatile("s_waitcnt vmcnt(8)" ::: "memory");
          else if (ks == 2) asm volatile("s_waitcnt vmcnt(4)" ::: "memory");
          else              asm volatile("s_waitcnt vmcnt(0)" ::: "memory");
          __builtin_amdgcn_sched_barrier(0);
        }
        const char* fp = dsm + fragB0 + ks * 4096 + mt * 1024;
        const half8 ah = *(const half8*)fp;
        const half8 al = *(const half8*)(fp + 2048);
#pragma unroll
        for (int t = 0; t < 4; ++t)
#pragma unroll
          for (int nt = 0; nt < 2; ++nt) {
            a_hh[t][nt] = MFMA16(ah, w_hi[t][nt][ks], a_hh[t][nt]);
            a_ll[t][nt] = MFMA16(al, w_hi[t][nt][ks], a_ll[t][nt]);
            a_ll[t][nt] = MFMA16(ah, w_lo[t][nt][ks], a_ll[t][nt]);
          }
        if (mt == mty) yac = MFMA16(ah, w_y[ks], yac);
      }
      // exchange writes for this mt pass
#pragma unroll
      for (int t = 0; t < 4; ++t)
#pragma unroll
        for (int nt = 0; nt < 2; ++nt) {
          const int base = ((t * 4 + v) * 32 + nt * 16 + n) * EXS + mt * 16 + q * 4;
          const float4v vv = a_hh[t][nt] + a_ll[t][nt] * LO_R;
          *(float2v*)(ex + base) = (float2v){vv[0], vv[1]};
          *(float2v*)(ex + base + 2) = (float2v){vv[2], vv[3]};
        }
      if (mt == mty) {
#pragma unroll
        for (int e = 0; e < 4; ++e) yp[(v * 16 + q * 4 + e) * 17 + n] = yac[e];
      }
    }
    __syncthreads();

    // ---- reduce 4 K-quarter partials + bias, gate in fp32; y-reduce to regs ----
    float pre[4][4];
#pragma unroll
    for (int t = 0; t < 4; ++t)
#pragma unroll
      for (int cc = 0; cc < 4; ++cc) {
        float acc = bias[t][cc];
#pragma unroll
        for (int w = 0; w < 4; ++w) acc += ex[((t * 4 + w) * 32 + c0 + cc) * EXS + rl];
        pre[t][cc] = acc;
      }
    float yv = by0;
#pragma unroll
    for (int w = 0; w < 4; ++w) yv += yp[(w * 16 + r16) * 17 + c16];

    half4 hiv, lov;
#pragma unroll
    for (int cc = 0; cc < 4; ++cc) {
      const float r = sigm(pre[0][cc]);
      const float z = sigm(pre[1][cc]);
      const float nn = tanh_(fmaf(r, pre[3][cc], pre[2][cc]));
      const float hn = fmaf(z, hreg[cc] - nn, nn);  // (1-z)*n + z*h
      hreg[cc] = hn;
      const f16 hi = (f16)hn;
      hiv[cc] = hi;
      lov[cc] = (f16)((hn - (float)hi) * LO_S);
    }
    {
      // write-through (sc1) 8B stores, wave-dense pattern, into this member's block
      char* ph = (char*)hx + (size_t)(s & 1) * 1048576 + recHi;
      __hip_atomic_store((uint64_t*)ph, __builtin_bit_cast(uint64_t, hiv),
                         __ATOMIC_RELAXED, __HIP_MEMORY_SCOPE_AGENT);
      __hip_atomic_store((uint64_t*)(ph + 2048), __builtin_bit_cast(uint64_t, lov),
                         __ATOMIC_RELAXED, __HIP_MEMORY_SCOPE_AGENT);
    }
    asm volatile("s_waitcnt vmcnt(0)" ::: "memory");  // h stores acked at L3
    __syncthreads();                                  // ... for all 4 waves
    if (tid == 0)  // single-writer monotone step tag (no RMW)
      __hip_atomic_store(fb + m, s, __ATOMIC_RELAXED, __HIP_MEMORY_SCOPE_AGENT);

    // ---- y_{s-1} -> out[:, s-2, :] from regs (publish shadow) ----
    if (s >= 2)
      __builtin_nontemporal_store(yv, out + outRowB + (size_t)(s - 2) * Fsz);
    // no end-of-step barrier: next iteration's per-wave flag polls gate progress
  }
}

extern "C" void kernel_launch(void* const* d_in, const int* in_sizes, int n_in,
                              void* d_out, int out_size, void* d_ws, size_t ws_size,
                              hipStream_t stream) {
  (void)in_sizes; (void)n_in; (void)out_size; (void)ws_size;
  const float* h0  = (const float*)d_in[1];
  const float* Wih = (const float*)d_in[2];
  const float* Whh = (const float*)d_in[3];
  const float* bih = (const float*)d_in[4];
  const float* bhh = (const float*)d_in[5];
  const float* Wd  = (const float*)d_in[6];
  const float* bd  = (const float*)d_in[7];
  float* out = (float*)d_out;
  char* ws = (char*)d_ws;

  f16* whiF    = (f16*)(ws + OFF_WHI);
  f16* wloF    = (f16*)(ws + OFF_WLO);
  float* biasP = (float*)(ws + OFF_BIAS);
  f16* hx      = (f16*)(ws + OFF_HX);
  int* flags   = (int*)(ws + OFF_FLAGS);

  hipFuncSetAttribute((const void*)k_main, hipFuncAttributeMaxDynamicSharedMemorySize,
                      LDS_TOT);
  k_pack<<<dim3(2, NPACK), 256, 0, stream>>>(Wih, Whh, Wd, whiF, wloF);
  k_init<<<1024, 256, 0, stream>>>(h0, Wih, bih, bhh, bd, hx, biasP, flags);
  k_main<<<256, 256, LDS_TOT, stream>>>(h0, whiF, wloF, biasP, hx, flags, out);
}